// Round 2
// baseline (3761.538 us; speedup 1.0000x reference)
//
#include <hip/hip_runtime.h>

// Volume (B=2, C=1, D=192, H=192, W=192) fp32 in/out.
// One kernel per opening step j=0..40: reads X=A_j (fp16; fp32 img at j=0),
// computes A_{j+1}=erode(X) (7-star min), D=dilate(A_{j+1}) (3^3 box max),
// delta=relu(X-D), skel-accumulates (fp16 in ws; j=40 writes fp32 d_out).
// ALL min/max run in packed fp16 (v_pk_*_f16): min/max are selections, so
// fp16 rounding commutes with them -> bit-identical to round-after-select.
// delta/skel arithmetic stays fp32.
//
// Mapping: block = 192 threads = one full y-column at fixed (x-group g, z-chunk,
// batch). y-halo via LDS exchange (1 barrier/plane, double-buffered slab);
// x-halo via neighbor-group vector loads (no shfl, no scalar patch loads);
// z-halo via 5-deep register pipeline (outputs z=p-2 when plane p loads).
//
// R1 fix: hm8[k] = min(strip[k..k+2]) is CENTERED at col 4g-1+k, so the
// cols -1..4 extraction is pairs (0,1),(2,3),(4,5) — previous round used
// (1,2),(3,4),(5,6) (off-by-one vs a0/aU/aD alignment) -> absmax 0.706.
// Also: skel input now prefetched one plane ahead (was same-iteration load).

#define Dn 192
#define Hn 192
#define Wn 192
#define PLANE (Hn * Wn)
#define TOTAL_ELEMS (2 * Dn * Hn * Wn)
#define GX 48                // x groups of 4
#define ZPT 16               // z planes per thread
#define ZC (Dn / ZPT)        // 12 z-chunks
#define NBLK (GX * ZC * 2)   // 1152 blocks
#define NITER (ZPT + 4)      // 20 pipeline iterations

typedef _Float16 h2 __attribute__((ext_vector_type(2)));
typedef _Float16 h4 __attribute__((ext_vector_type(4)));
typedef _Float16 h8 __attribute__((ext_vector_type(8)));

static __device__ __forceinline__ h2 h2min(h2 a, h2 b) { return __builtin_elementwise_min(a, b); }
static __device__ __forceinline__ h2 h2max(h2 a, h2 b) { return __builtin_elementwise_max(a, b); }
static __device__ __forceinline__ h8 h8min(h8 a, h8 b) { return __builtin_elementwise_min(a, b); }
static __device__ __forceinline__ unsigned int u32(h2 v) { return __builtin_bit_cast(unsigned int, v); }
static __device__ __forceinline__ h2 h2c(unsigned int v) { return __builtin_bit_cast(h2, v); }

// XCD-aware swizzle: contiguous z-slabs per XCD for L2/LLC locality.
template <int CHUNK>
__device__ __forceinline__ int swizzle(int bid) {
    return (bid & 7) * CHUNK + (bid >> 3);
}

template <bool FIRST, bool LAST>
__global__ __launch_bounds__(192, 4) void step_k(const void* __restrict__ X_,
                                                 const _Float16* Sin,
                                                 void* Sout_,
                                                 _Float16* __restrict__ Aout) {
    const float* Xf = (const float*)X_;
    const _Float16* Xh = (const _Float16*)X_;
    _Float16* Sh = (_Float16*)Sout_;
    float* Sf = (float*)Sout_;

    const int bid = swizzle<NBLK / 8>((int)blockIdx.x);
    const int g = bid % GX;            // block-uniform
    const int t2 = bid / GX;
    const int zc = t2 % ZC;
    const int b = t2 / ZC;
    const int y = threadIdx.x;         // 0..191
    const int z0 = zc * ZPT;
    const int cbase = b * (Dn * PLANE) + y * Wn + g * 4;

    // LDS exchange slab: [slot][y][0..2]=raw mid-strip a (cols -1..4),
    // [3..5]=E1 (cols -1..4). Pad to 7 words: stride 7 coprime 32 banks.
    __shared__ unsigned int sh[2][Hn][7];
    const int yu = (y < Hn - 1) ? y + 1 : y;   // clamp = replicate (neutral)
    const int yd = (y > 0) ? y - 1 : y;

    // z-pipeline state (packed fp16, cols -1..4 per 3-reg set)
    h2 aM2[3], aM1[3], hmM1[3], aUM1[3], aDM1[3];
    h2 xcM1[2], xcM2[2], e1cM1[2], mM1[2], mM2[2];

    // raw prefetch regs (next plane), 1-iteration software pipeline
    h4 Cn = {}, Ln = {}, Rn = {};
    float4 Cfn, Lfn, Rfn;
    h4 sP = {};   // skel input for this iteration's output (prefetched)

    auto issue = [&](int p) {
        int pz = p < 0 ? 0 : (p > Dn - 1 ? Dn - 1 : p);  // z-clamp (neutral)
        int off = cbase + pz * PLANE;
        if (FIRST) {
            Cfn = *(const float4*)(Xf + off);
            Lfn = (g > 0) ? *(const float4*)(Xf + off - 4) : Cfn;
            Rfn = (g < GX - 1) ? *(const float4*)(Xf + off + 4) : Cfn;
        } else {
            Cn = *(const h4*)(Xh + off);
            Ln = (g > 0) ? *(const h4*)(Xh + off - 4) : Cn;
            Rn = (g < GX - 1) ? *(const h4*)(Xh + off + 4) : Cn;
        }
    };
    issue(z0 - 2);

#pragma unroll
    for (int i = 0; i < NITER; ++i) {
        const int p = z0 - 2 + i;   // plane being integrated this iteration
        const int zo = p - 2;       // output plane this iteration (i >= 4)

        // ---- build 8-col strip [x-2..x+5] of row y, plane p (fp16)
        h8 strip;
        if (FIRST) {
            h8 t = {(_Float16)Lfn.z, (_Float16)Lfn.w,
                    (_Float16)Cfn.x, (_Float16)Cfn.y, (_Float16)Cfn.z, (_Float16)Cfn.w,
                    (_Float16)Rfn.x, (_Float16)Rfn.y};
            strip = t;
        } else {
            h8 t0 = __builtin_shufflevector(Ln, Cn, 2, 3, 4, 5, 6, 7, 7, 7);
            h8 t1 = __builtin_shufflevector(Rn, Rn, 0, 1, 0, 1, 0, 1, 0, 1);
            strip = __builtin_shufflevector(t0, t1, 0, 1, 2, 3, 4, 5, 8, 9);
        }
        // x-boundary: replicate edge col (neutral for min; E1 fixed below for max)
        if (g == 0)      strip = __builtin_shufflevector(strip, strip, 2, 2, 2, 3, 4, 5, 6, 7);
        if (g == GX - 1) strip = __builtin_shufflevector(strip, strip, 0, 1, 2, 3, 4, 5, 5, 5);

        // ---- issue next plane's loads (consumed next iteration)
        if (i + 1 < NITER) issue(p + 1);

        // ---- prefetch skel input for the NEXT iteration's output (zo+1 = p-1)
        h4 sN = {};
        if (!FIRST && i >= 3 && i + 1 < NITER)
            sN = *(const h4*)(Sin + cbase + (p - 1) * PLANE);

        // ---- per-plane summaries: hm = horizontal min3 (cols -1..4),
        //      a = raw mid strip (cols -1..4), xc = center cols 0..3
        h8 sA = __builtin_shufflevector(strip, strip, 1, 2, 3, 4, 5, 6, 7, 7);
        h8 sB = __builtin_shufflevector(strip, strip, 2, 3, 4, 5, 6, 7, 7, 7);
        h8 hm8 = h8min(h8min(strip, sA), sB);   // hm8[k] centered at col 4g-1+k
        h2 a0[3] = {__builtin_shufflevector(strip, strip, 1, 2),
                    __builtin_shufflevector(strip, strip, 3, 4),
                    __builtin_shufflevector(strip, strip, 5, 6)};
        h2 hm0[3] = {__builtin_shufflevector(hm8, hm8, 0, 1),
                     __builtin_shufflevector(hm8, hm8, 2, 3),
                     __builtin_shufflevector(hm8, hm8, 4, 5)};
        h2 xc0[2] = {__builtin_shufflevector(strip, strip, 2, 3),
                     __builtin_shufflevector(strip, strip, 4, 5)};

        // ---- E1(p-1): 7-star erosion, cols -1..4
        h2 e1[3];
        if (i >= 2) {
#pragma unroll
            for (int k = 0; k < 3; ++k)
                e1[k] = h2min(h2min(hmM1[k], aM2[k]),
                              h2min(h2min(aUM1[k], aDM1[k]), a0[k]));
            // x-boundary: E1 outside the volume must be neutral for the max;
            // replicate the edge E1 value (it's included in the max anyway).
            if (g == 0)      e1[0] = __builtin_shufflevector(e1[0], e1[0], 1, 1);
            if (g == GX - 1) e1[2] = __builtin_shufflevector(e1[2], e1[2], 0, 0);
        }

        // ---- LDS exchange (double-buffered, ONE barrier per plane)
        const int sl = i & 1;
        sh[sl][y][0] = u32(a0[0]);
        sh[sl][y][1] = u32(a0[1]);
        sh[sl][y][2] = u32(a0[2]);
        if (i >= 2) {
            sh[sl][y][3] = u32(e1[0]);
            sh[sl][y][4] = u32(e1[1]);
            sh[sl][y][5] = u32(e1[2]);
        }
        __syncthreads();
        h2 aU0[3] = {h2c(sh[sl][yu][0]), h2c(sh[sl][yu][1]), h2c(sh[sl][yu][2])};
        h2 aD0[3] = {h2c(sh[sl][yd][0]), h2c(sh[sl][yd][1]), h2c(sh[sl][yd][2])};

        // ---- m(p-1) = in-plane 3x3 max of E1 (cols 0..3); E1 center extract
        h2 m0[2], e1c0[2];
        if (i >= 2) {
            h2 eU0 = h2c(sh[sl][yu][3]), eU1 = h2c(sh[sl][yu][4]), eU2 = h2c(sh[sl][yu][5]);
            h2 eD0 = h2c(sh[sl][yd][3]), eD1 = h2c(sh[sl][yd][4]), eD2 = h2c(sh[sl][yd][5]);
            h2 vm0 = h2max(e1[0], h2max(eU0, eD0));   // cols (-1,0)
            h2 vm1 = h2max(e1[1], h2max(eU1, eD1));   // cols (1,2)
            h2 vm2 = h2max(e1[2], h2max(eU2, eD2));   // cols (3,4)
            h2 mid01 = __builtin_shufflevector(vm0, vm1, 1, 2);  // (0,1)
            h2 mid23 = __builtin_shufflevector(vm1, vm2, 1, 2);  // (2,3)
            m0[0] = h2max(h2max(vm0, mid01), vm1);    // out cols (0,1)
            m0[1] = h2max(h2max(vm1, mid23), vm2);    // out cols (2,3)
            e1c0[0] = __builtin_shufflevector(e1[0], e1[1], 1, 2);
            e1c0[1] = __builtin_shufflevector(e1[1], e1[2], 1, 2);
        }

        // ---- output z = p-2: D = max_z(m), delta, skel update, stores
        if (i >= 4) {
            const int offo = cbase + zo * PLANE;
            const bool zlo = (zo == 0);
            const bool zhi = (zo == Dn - 1);
            h2 mzA0 = zlo ? mM1[0] : mM2[0];   // m(z-1) -> replicate m(z) at z=0
            h2 mzA1 = zlo ? mM1[1] : mM2[1];
            h2 mzC0 = zhi ? mM1[0] : m0[0];    // m(z+1) -> replicate m(z) at z=191
            h2 mzC1 = zhi ? mM1[1] : m0[1];
            h2 d01 = h2max(h2max(mzA0, mM1[0]), mzC0);
            h2 d23 = h2max(h2max(mzA1, mM1[1]), mzC1);

            float ex0 = (float)xcM2[0].x, ex1 = (float)xcM2[0].y;
            float ex2 = (float)xcM2[1].x, ex3 = (float)xcM2[1].y;
            float dl0 = (float)d01.x, dl1 = (float)d01.y;
            float dl2 = (float)d23.x, dl3 = (float)d23.y;
            float de0 = fmaxf(ex0 - dl0, 0.f);
            float de1 = fmaxf(ex1 - dl1, 0.f);
            float de2 = fmaxf(ex2 - dl2, 0.f);
            float de3 = fmaxf(ex3 - dl3, 0.f);
            float s0, s1, s2, s3;
            if (FIRST) {
                s0 = de0; s1 = de1; s2 = de2; s3 = de3;
            } else {
                s0 = (float)sP.x; s1 = (float)sP.y;
                s2 = (float)sP.z; s3 = (float)sP.w;
                s0 += fmaxf(de0 - s0 * de0, 0.f);
                s1 += fmaxf(de1 - s1 * de1, 0.f);
                s2 += fmaxf(de2 - s2 * de2, 0.f);
                s3 += fmaxf(de3 - s3 * de3, 0.f);
            }
            if (LAST) {
                *(float4*)(Sf + offo) = make_float4(s0, s1, s2, s3);
            } else {
                h4 sv;
                sv.x = (_Float16)s0; sv.y = (_Float16)s1;
                sv.z = (_Float16)s2; sv.w = (_Float16)s3;
                *(h4*)(Sh + offo) = sv;
                h4 av = __builtin_shufflevector(e1cM1[0], e1cM1[1], 0, 1, 2, 3);
                *(h4*)(Aout + offo) = av;   // A_{j+1}[z] = erosion center
            }
        }

        // ---- rotate pipeline state
#pragma unroll
        for (int k = 0; k < 3; ++k) {
            aM2[k] = aM1[k]; aM1[k] = a0[k];
            hmM1[k] = hm0[k]; aUM1[k] = aU0[k]; aDM1[k] = aD0[k];
        }
        xcM2[0] = xcM1[0]; xcM2[1] = xcM1[1];
        xcM1[0] = xc0[0];  xcM1[1] = xc0[1];
        if (i >= 2) {
            mM2[0] = mM1[0]; mM2[1] = mM1[1];
            mM1[0] = m0[0];  mM1[1] = m0[1];
            e1cM1[0] = e1c0[0]; e1cM1[1] = e1c0[1];
        }
        sP = sN;
    }
}

extern "C" void kernel_launch(void* const* d_in, const int* in_sizes, int n_in,
                              void* d_out, int out_size, void* d_ws, size_t ws_size,
                              hipStream_t stream) {
    const float* img = (const float*)d_in[0];
    _Float16* B0 = (_Float16*)d_ws;
    _Float16* B1 = B0 + TOTAL_ELEMS;
    _Float16* S  = B1 + TOTAL_ELEMS;   // 3 x 28.3 MB workspace (fp16)

    // Step j: X=A_j -> A_{j+1}=erode(X), skel += f(relu(X - dilate(A_{j+1}))).
    // j=0 reads fp32 img, initializes skel. j=40 writes fp32 skel to d_out.
    step_k<true, false><<<NBLK, 192, 0, stream>>>(img, nullptr, S, B0);
    _Float16* a = B0;
    _Float16* nb = B1;
    for (int j = 1; j <= 39; ++j) {
        step_k<false, false><<<NBLK, 192, 0, stream>>>(a, S, S, nb);
        _Float16* t = a; a = nb; nb = t;
    }
    step_k<false, true><<<NBLK, 192, 0, stream>>>(a, S, d_out, nullptr);
}

// Round 3
// 1122.988 us; speedup vs baseline: 3.3496x; 3.3496x over previous
//
#include <hip/hip_runtime.h>

// Volume (B=2, C=1, D=192, H=192, W=192) fp32 in/out.
// One kernel per opening step j=0..40: reads X=A_j (fp16; fp32 img at j=0),
// computes A_{j+1}=erode(X) (7-star min), D=dilate(A_{j+1}) (3^3 box max),
// delta=relu(X-D), skel-accumulates (fp16 in ws; j=40 writes fp32 d_out).
// Packed-fp16 min/max (selections commute with monotone rounding).
//
// R3: axis relabel of the R2-verified pipeline. Thread index = x (contiguous
// across lanes -> every global access coalesced); vector axis = y (4 rows per
// thread, scalar u16 accesses, each wave-coalesced 128B); LDS exchanges the
// x-halo (thread t+-1); z via 5-deep register pipeline. R2's y-mapping put
// 384B between consecutive lanes -> 64 lines per wave-load (8x inflation),
// VALUBusy 8.8%. Algorithm unchanged (verified absmax 0.0039).

#define Dn 192
#define Hn 192
#define Wn 192
#define PLANE (Hn * Wn)
#define TOTAL_ELEMS (2 * Dn * Hn * Wn)
#define NYG (Hn / 4)         // 48 y-groups of 4 rows
#define ZPT 8                // z planes per thread
#define ZC (Dn / ZPT)        // 24 z-chunks
#define NBLK (NYG * ZC * 2)  // 2304 blocks
#define NITER (ZPT + 4)      // 12 pipeline iterations

typedef _Float16 h2 __attribute__((ext_vector_type(2)));
typedef _Float16 h4 __attribute__((ext_vector_type(4)));

static __device__ __forceinline__ h2 h2min(h2 a, h2 b) { return __builtin_elementwise_min(a, b); }
static __device__ __forceinline__ h2 h2max(h2 a, h2 b) { return __builtin_elementwise_max(a, b); }
static __device__ __forceinline__ unsigned int u32(h2 v) { return __builtin_bit_cast(unsigned int, v); }
static __device__ __forceinline__ h2 h2c(unsigned int v) { return __builtin_bit_cast(h2, v); }

// XCD-aware swizzle: contiguous slabs per XCD for L2/LLC locality.
template <int CHUNK>
__device__ __forceinline__ int swizzle(int bid) {
    return (bid & 7) * CHUNK + (bid >> 3);
}

template <bool FIRST, bool LAST>
__global__ __launch_bounds__(192, 4) void step_k(const void* __restrict__ X_,
                                                 const _Float16* Sin,
                                                 void* Sout_,
                                                 _Float16* __restrict__ Aout) {
    const float* Xf = (const float*)X_;
    const _Float16* Xh = (const _Float16*)X_;
    _Float16* Sh = (_Float16*)Sout_;
    float* Sf = (float*)Sout_;

    const int bid = swizzle<NBLK / 8>((int)blockIdx.x);
    const int gy = bid % NYG;          // block-uniform
    const int t2 = bid / NYG;
    const int zc = t2 % ZC;
    const int b = t2 / ZC;
    const int x = threadIdx.x;         // 0..191, contiguous across lanes
    const int y0 = gy * 4;
    const int z0 = zc * ZPT;
    const int cbase = b * (Dn * PLANE) + y0 * Wn + x;

    // Clamped row offsets for strip rows k=0..7 (y = y0-2+k). Clamp-at-load
    // implements the y-replicate boundary (R2's strip shuffles) automatically.
    int roff[8];
#pragma unroll
    for (int k = 0; k < 8; ++k) {
        int ry = y0 - 2 + k;
        ry = ry < 0 ? 0 : (ry > Hn - 1 ? Hn - 1 : ry);
        roff[k] = (ry - y0) * Wn;
    }

    // LDS x-halo exchange: [slot][x][0..2]=raw mid-strip a (y-slots -1..4),
    // [3..5]=E1. Stride 7 words: lanes x, x*7 mod 32 -> 2 lanes/bank (free).
    __shared__ unsigned int sh[2][192][7];
    const int xu = (x < Wn - 1) ? x + 1 : x;   // clamp = replicate (neutral)
    const int xd = (x > 0) ? x - 1 : x;

    // z-pipeline state (packed fp16 pairs along y, slots -1..4 per 3-reg set)
    h2 aM2[3], aM1[3], hmM1[3], aUM1[3], aDM1[3];
    h2 xcM1[2], xcM2[2], e1cM1[2], mM1[2], mM2[2];

    // raw prefetch regs (next plane): 8 strip rows
    _Float16 hP[8];
    float fP[8];
    h4 sP = {};   // skel input for this iteration's output (prefetched)

    auto issue = [&](int p) {
        int pz = p < 0 ? 0 : (p > Dn - 1 ? Dn - 1 : p);  // z-clamp (neutral)
        if (FIRST) {
            const float* pp = Xf + cbase + pz * PLANE;
#pragma unroll
            for (int k = 0; k < 8; ++k) fP[k] = pp[roff[k]];
        } else {
            const _Float16* pp = Xh + cbase + pz * PLANE;
#pragma unroll
            for (int k = 0; k < 8; ++k) hP[k] = pp[roff[k]];
        }
    };
    issue(z0 - 2);

#pragma unroll
    for (int i = 0; i < NITER; ++i) {
        const int p = z0 - 2 + i;   // plane being integrated this iteration
        const int zo = p - 2;       // output plane this iteration (i >= 4)

        // ---- strip: 8 y-values [y0-2..y0+5] at (x, plane p), fp16
        _Float16 s[8];
#pragma unroll
        for (int k = 0; k < 8; ++k) s[k] = FIRST ? (_Float16)fP[k] : hP[k];

        // ---- issue next plane's loads (consumed next iteration)
        if (i + 1 < NITER) issue(p + 1);

        // ---- prefetch skel input for the NEXT iteration's output (= p-1)
        h4 sN = {};
        if (!FIRST && i >= 3 && i + 1 < NITER) {
            const _Float16* sp = Sin + cbase + (p - 1) * PLANE;
            sN.x = sp[0]; sN.y = sp[Wn]; sN.z = sp[2 * Wn]; sN.w = sp[3 * Wn];
        }

        // ---- per-plane summaries (pairs along y):
        // P[k]=(s[k],s[k+1]); a = raw slots -1..4; hm = y-min3 slots -1..4;
        // xc = center slots 0..3
        h2 P[7];
#pragma unroll
        for (int k = 0; k < 7; ++k) { h2 t = {s[k], s[k + 1]}; P[k] = t; }
        h2 a0[3] = {P[1], P[3], P[5]};
        h2 hm0[3];
#pragma unroll
        for (int j = 0; j < 3; ++j)
            hm0[j] = h2min(P[2 * j], h2min(P[2 * j + 1], P[2 * j + 2]));
        h2 xc0[2] = {P[2], P[4]};

        // ---- E1(p-1): 7-star erosion, y-slots -1..4
        h2 e1[3];
        if (i >= 2) {
#pragma unroll
            for (int k = 0; k < 3; ++k)
                e1[k] = h2min(h2min(hmM1[k], aM2[k]),
                              h2min(h2min(aUM1[k], aDM1[k]), a0[k]));
            // y-boundary: fictitious E1 outside the volume must be neutral
            // for the max; replicate the edge E1 value.
            if (gy == 0)       e1[0] = __builtin_shufflevector(e1[0], e1[0], 1, 1);
            if (gy == NYG - 1) e1[2] = __builtin_shufflevector(e1[2], e1[2], 0, 0);
        }

        // ---- LDS x-halo exchange (double-buffered, ONE barrier per plane)
        const int sl = i & 1;
        sh[sl][x][0] = u32(a0[0]);
        sh[sl][x][1] = u32(a0[1]);
        sh[sl][x][2] = u32(a0[2]);
        if (i >= 2) {
            sh[sl][x][3] = u32(e1[0]);
            sh[sl][x][4] = u32(e1[1]);
            sh[sl][x][5] = u32(e1[2]);
        }
        __syncthreads();
        h2 aU0[3] = {h2c(sh[sl][xu][0]), h2c(sh[sl][xu][1]), h2c(sh[sl][xu][2])};
        h2 aD0[3] = {h2c(sh[sl][xd][0]), h2c(sh[sl][xd][1]), h2c(sh[sl][xd][2])};

        // ---- m(p-1) = in-plane 3x3 max of E1 (y-slots 0..3); E1 center
        h2 m0[2], e1c0[2];
        if (i >= 2) {
            h2 eU0 = h2c(sh[sl][xu][3]), eU1 = h2c(sh[sl][xu][4]), eU2 = h2c(sh[sl][xu][5]);
            h2 eD0 = h2c(sh[sl][xd][3]), eD1 = h2c(sh[sl][xd][4]), eD2 = h2c(sh[sl][xd][5]);
            h2 vm0 = h2max(e1[0], h2max(eU0, eD0));   // y-slots (-1,0)
            h2 vm1 = h2max(e1[1], h2max(eU1, eD1));   // (1,2)
            h2 vm2 = h2max(e1[2], h2max(eU2, eD2));   // (3,4)
            h2 mid01 = __builtin_shufflevector(vm0, vm1, 1, 2);  // (0,1)
            h2 mid23 = __builtin_shufflevector(vm1, vm2, 1, 2);  // (2,3)
            m0[0] = h2max(h2max(vm0, mid01), vm1);    // out y (0,1)
            m0[1] = h2max(h2max(vm1, mid23), vm2);    // out y (2,3)
            e1c0[0] = __builtin_shufflevector(e1[0], e1[1], 1, 2);
            e1c0[1] = __builtin_shufflevector(e1[1], e1[2], 1, 2);
        }

        // ---- output z = p-2: D = max_z(m), delta, skel update, stores
        if (i >= 4) {
            const int offo = cbase + zo * PLANE;
            const bool zlo = (zo == 0);
            const bool zhi = (zo == Dn - 1);
            h2 mzA0 = zlo ? mM1[0] : mM2[0];   // m(z-1) -> replicate at z=0
            h2 mzA1 = zlo ? mM1[1] : mM2[1];
            h2 mzC0 = zhi ? mM1[0] : m0[0];    // m(z+1) -> replicate at z=191
            h2 mzC1 = zhi ? mM1[1] : m0[1];
            h2 d01 = h2max(h2max(mzA0, mM1[0]), mzC0);
            h2 d23 = h2max(h2max(mzA1, mM1[1]), mzC1);

            float ex0 = (float)xcM2[0].x, ex1 = (float)xcM2[0].y;
            float ex2 = (float)xcM2[1].x, ex3 = (float)xcM2[1].y;
            float dl0 = (float)d01.x, dl1 = (float)d01.y;
            float dl2 = (float)d23.x, dl3 = (float)d23.y;
            float de0 = fmaxf(ex0 - dl0, 0.f);
            float de1 = fmaxf(ex1 - dl1, 0.f);
            float de2 = fmaxf(ex2 - dl2, 0.f);
            float de3 = fmaxf(ex3 - dl3, 0.f);
            float s0, s1, s2, s3;
            if (FIRST) {
                s0 = de0; s1 = de1; s2 = de2; s3 = de3;
            } else {
                s0 = (float)sP.x; s1 = (float)sP.y;
                s2 = (float)sP.z; s3 = (float)sP.w;
                s0 += fmaxf(de0 - s0 * de0, 0.f);
                s1 += fmaxf(de1 - s1 * de1, 0.f);
                s2 += fmaxf(de2 - s2 * de2, 0.f);
                s3 += fmaxf(de3 - s3 * de3, 0.f);
            }
            if (LAST) {
                Sf[offo] = s0; Sf[offo + Wn] = s1;
                Sf[offo + 2 * Wn] = s2; Sf[offo + 3 * Wn] = s3;
            } else {
                Sh[offo] = (_Float16)s0;
                Sh[offo + Wn] = (_Float16)s1;
                Sh[offo + 2 * Wn] = (_Float16)s2;
                Sh[offo + 3 * Wn] = (_Float16)s3;
                Aout[offo] = e1cM1[0].x;            // A_{j+1}[z] = erosion center
                Aout[offo + Wn] = e1cM1[0].y;
                Aout[offo + 2 * Wn] = e1cM1[1].x;
                Aout[offo + 3 * Wn] = e1cM1[1].y;
            }
        }

        // ---- rotate pipeline state
#pragma unroll
        for (int k = 0; k < 3; ++k) {
            aM2[k] = aM1[k]; aM1[k] = a0[k];
            hmM1[k] = hm0[k]; aUM1[k] = aU0[k]; aDM1[k] = aD0[k];
        }
        xcM2[0] = xcM1[0]; xcM2[1] = xcM1[1];
        xcM1[0] = xc0[0];  xcM1[1] = xc0[1];
        if (i >= 2) {
            mM2[0] = mM1[0]; mM2[1] = mM1[1];
            mM1[0] = m0[0];  mM1[1] = m0[1];
            e1cM1[0] = e1c0[0]; e1cM1[1] = e1c0[1];
        }
        sP = sN;
    }
}

extern "C" void kernel_launch(void* const* d_in, const int* in_sizes, int n_in,
                              void* d_out, int out_size, void* d_ws, size_t ws_size,
                              hipStream_t stream) {
    const float* img = (const float*)d_in[0];
    _Float16* B0 = (_Float16*)d_ws;
    _Float16* B1 = B0 + TOTAL_ELEMS;
    _Float16* S  = B1 + TOTAL_ELEMS;   // 3 x 28.3 MB workspace (fp16)

    // Step j: X=A_j -> A_{j+1}=erode(X), skel += f(relu(X - dilate(A_{j+1}))).
    // j=0 reads fp32 img, initializes skel. j=40 writes fp32 skel to d_out.
    step_k<true, false><<<NBLK, 192, 0, stream>>>(img, nullptr, S, B0);
    _Float16* a = B0;
    _Float16* nb = B1;
    for (int j = 1; j <= 39; ++j) {
        step_k<false, false><<<NBLK, 192, 0, stream>>>(a, S, S, nb);
        _Float16* t = a; a = nb; nb = t;
    }
    step_k<false, true><<<NBLK, 192, 0, stream>>>(a, S, d_out, nullptr);
}

// Round 4
// 963.984 us; speedup vs baseline: 3.9021x; 1.1649x over previous
//
#include <hip/hip_runtime.h>

// Volume (B=2, C=1, D=192, H=192, W=192) fp32 in/out.
// R4: fuse TWO opening steps per kernel. Per fused kernel (steps j, j+1):
//   E1 = erode(X) (7-star min), D1 = dilate(E1) (3^3 max), delta1 = relu(X-D1)
//   E2 = erode(E1),             D2 = dilate(E2),           delta2 = relu(E1-D2)
//   s1 = skelupd(sIn, delta1); s2 = skelupd(s1, delta2)
//   writes: Aout = E2 (= A_{j+2}), Sout = s2.  A_{j+1} never hits memory;
//   S round-trips once per TWO steps -> traffic 113 MB / 2 steps (was /1).
// Packed-fp16 min/max (selections commute with monotone rounding); skel math fp32.
//
// Mapping (R3-verified): thread = x (coalesced), vector h2 pairs along y
// (4 output rows/block + halo), LDS exchanges x-halo (1 barrier/plane),
// z via register pipeline. Output z = p-3 when plane p is loaded.
//
// Slot/age ledger (iteration i, p = z0-3+i, zo = p-3):
//   X strip: y-slots -3..6 (10 rows)  E1: slots -2..5  t=E1 trim: -1..4
//   E2: slots -1..4   m1,m2,xc,e1c,e2c: slots 0..3
//   fresh: X(p), hm(p), E1(p-1), hm1(p-1), E2(p-2), m1(p-1), m2(p-2)
//   at output zo: m1(z+1)=m1M1 m1(z)=m1M2 m1(z-1)=m1M3 ; m2(z+1)=m2_0 fresh,
//   m2(z)=m2M1 m2(z-1)=m2M2 ; xc(z)=xcM3 ; e1c(z)=e1cM2 ; e2c(z)=e2cM1.
// Replicate padding is neutral for BOTH min and max (replicated value is
// already inside the window); fictitious clamped-z E1 planes are >= the true
// E1 in-window values so neutral for E2's min; D1/D2 z-boundaries use explicit
// zlo/zhi selects (R3 pattern).

#define Dn 192
#define Hn 192
#define Wn 192
#define PLANE (Hn * Wn)
#define TOTAL_ELEMS (2 * Dn * Hn * Wn)
#define NYG (Hn / 4)         // 48 y-groups of 4 rows
#define ZPT 8                // z planes per thread
#define ZC (Dn / ZPT)        // 24 z-chunks
#define NBLK (NYG * ZC * 2)  // 2304 blocks
#define NITER2 (ZPT + 6)     // fused-2 pipeline iterations
#define NITER1 (ZPT + 4)     // single-step pipeline iterations

typedef _Float16 h2 __attribute__((ext_vector_type(2)));
typedef _Float16 h4 __attribute__((ext_vector_type(4)));

static __device__ __forceinline__ h2 h2min(h2 a, h2 b) { return __builtin_elementwise_min(a, b); }
static __device__ __forceinline__ h2 h2max(h2 a, h2 b) { return __builtin_elementwise_max(a, b); }
static __device__ __forceinline__ h2 h2min3(h2 a, h2 b, h2 c) { return h2min(h2min(a, b), c); }
static __device__ __forceinline__ h2 h2max3(h2 a, h2 b, h2 c) { return h2max(h2max(a, b), c); }
static __device__ __forceinline__ unsigned int u32(h2 v) { return __builtin_bit_cast(unsigned int, v); }
static __device__ __forceinline__ h2 h2c(unsigned int v) { return __builtin_bit_cast(h2, v); }

template <int CHUNK>
__device__ __forceinline__ int swizzle(int bid) {
    return (bid & 7) * CHUNK + (bid >> 3);
}

// ---------------- fused two-step kernel ----------------
template <bool FIRST>
__global__ __launch_bounds__(192, 4) void fused2_k(const void* __restrict__ X_,
                                                   const _Float16* Sin,
                                                   _Float16* Sout,
                                                   _Float16* __restrict__ Aout) {
    const float* Xf = (const float*)X_;
    const _Float16* Xh = (const _Float16*)X_;

    const int bid = swizzle<NBLK / 8>((int)blockIdx.x);
    const int gy = bid % NYG;
    const int t2 = bid / NYG;
    const int zc = t2 % ZC;
    const int b = t2 / ZC;
    const int x = threadIdx.x;         // 0..191, contiguous across lanes
    const int y0 = gy * 4;
    const int z0 = zc * ZPT;
    const int cbase = b * (Dn * PLANE) + y0 * Wn + x;

    // Clamped row offsets, rows y0-3 .. y0+6 (clamp = y-replicate boundary).
    int roff[10];
#pragma unroll
    for (int k = 0; k < 10; ++k) {
        int ry = y0 - 3 + k;
        ry = ry < 0 ? 0 : (ry > Hn - 1 ? Hn - 1 : ry);
        roff[k] = (ry - y0) * Wn;
    }

    // LDS: [slot][x][0..3]=X slots -2..5, [4..6]=E1 trimmed slots -1..4,
    // [7..9]=E2 slots -1..4. Stride 11 (gcd(11,32)=1 -> 2 lanes/bank, free).
    __shared__ unsigned int sh[2][192][11];
    const int xu = (x < Wn - 1) ? x + 1 : x;
    const int xd = (x > 0) ? x - 1 : x;

    // pipeline state (all zero-init; early-iteration consumers are gated)
    h2 aM1[4] = {}, aM2[4] = {}, hmM1[4] = {}, aUM1[4] = {}, aDM1[4] = {};
    h2 e1M1t[3] = {}, e1M2t[3] = {}, hm1M1[3] = {}, e1UM1[3] = {}, e1DM1[3] = {};
    h2 m1M1[2] = {}, m1M2[2] = {}, m1M3[2] = {};
    h2 m2M1[2] = {}, m2M2[2] = {};
    h2 xcM1[2] = {}, xcM2[2] = {}, xcM3[2] = {};
    h2 e1cM1[2] = {}, e1cM2[2] = {}, e2cM1[2] = {};
    h4 sP = {};

    _Float16 hP[10];
    float fP[10];
    auto issue = [&](int p) {
        int pz = p < 0 ? 0 : (p > Dn - 1 ? Dn - 1 : p);  // z-clamp (neutral)
        if (FIRST) {
            const float* pp = Xf + cbase + pz * PLANE;
#pragma unroll
            for (int k = 0; k < 10; ++k) fP[k] = pp[roff[k]];
        } else {
            const _Float16* pp = Xh + cbase + pz * PLANE;
#pragma unroll
            for (int k = 0; k < 10; ++k) hP[k] = pp[roff[k]];
        }
    };
    issue(z0 - 3);

#pragma unroll
    for (int i = 0; i < NITER2; ++i) {
        const int p = z0 - 3 + i;
        const int zo = p - 3;

        // ---- strip: 10 y-values [y0-3..y0+6] at (x, plane p)
        _Float16 s[10];
#pragma unroll
        for (int k = 0; k < 10; ++k) s[k] = FIRST ? (_Float16)fP[k] : hP[k];

        if (i + 1 < NITER2) issue(p + 1);

        // skel prefetch for NEXT iteration's output (plane p-2)
        h4 sN = {};
        if (!FIRST && i >= 5 && i + 1 < NITER2) {
            const _Float16* sp = Sin + cbase + (p - 2) * PLANE;
            sN.x = sp[0]; sN.y = sp[Wn]; sN.z = sp[2 * Wn]; sN.w = sp[3 * Wn];
        }

        // ---- per-plane X summaries
        h2 P[9];
#pragma unroll
        for (int k = 0; k < 9; ++k) { h2 t = {s[k], s[k + 1]}; P[k] = t; }
        h2 a0[4] = {P[1], P[3], P[5], P[7]};           // X slots -2..5
        h2 hm0[4];
#pragma unroll
        for (int j = 0; j < 4; ++j)
            hm0[j] = h2min3(P[2 * j], P[2 * j + 1], P[2 * j + 2]);  // y-min3, slots -2..5
        h2 xc0[2] = {P[3], P[5]};                      // X center slots 0..3

        // ---- E1(p-1) slots -2..5 ; trim t slots -1..4 ; hm1(p-1) ; e1c(p-1)
        h2 e1[4] = {}, t[3] = {}, hm1_0[3] = {}, e1c0[2] = {};
        if (i >= 2) {
#pragma unroll
            for (int k = 0; k < 4; ++k)
                e1[k] = h2min3(h2min(hmM1[k], aM2[k]),
                               h2min(aUM1[k], aDM1[k]), a0[k]);
            if (gy == 0) { h2 v = {e1[1].x, e1[1].x}; e1[0] = v; }
            if (gy == NYG - 1) { h2 v = {e1[2].y, e1[2].y}; e1[3] = v; }
            t[0] = __builtin_shufflevector(e1[0], e1[1], 1, 2);
            t[1] = __builtin_shufflevector(e1[1], e1[2], 1, 2);
            t[2] = __builtin_shufflevector(e1[2], e1[3], 1, 2);
            hm1_0[0] = h2min3(e1[0], t[0], e1[1]);
            hm1_0[1] = h2min3(e1[1], t[1], e1[2]);
            hm1_0[2] = h2min3(e1[2], t[2], e1[3]);
            e1c0[0] = e1[1]; e1c0[1] = e1[2];
        }

        // ---- E2(p-2) slots -1..4 ; e2c(p-2)
        h2 e2[3] = {}, e2c0[2] = {};
        if (i >= 4) {
#pragma unroll
            for (int j = 0; j < 3; ++j)
                e2[j] = h2min3(h2min(hm1M1[j], e1M2t[j]),
                               h2min(e1UM1[j], e1DM1[j]), t[j]);
            if (gy == 0) { h2 v = {e2[0].y, e2[0].y}; e2[0] = v; }
            if (gy == NYG - 1) { h2 v = {e2[2].x, e2[2].x}; e2[2] = v; }
            e2c0[0] = __builtin_shufflevector(e2[0], e2[1], 1, 2);
            e2c0[1] = __builtin_shufflevector(e2[1], e2[2], 1, 2);
        }

        // ---- LDS exchange (double-buffered, ONE barrier per plane)
        const int sl = i & 1;
#pragma unroll
        for (int k = 0; k < 4; ++k) sh[sl][x][k] = u32(a0[k]);
        if (i >= 2) {
#pragma unroll
            for (int j = 0; j < 3; ++j) sh[sl][x][4 + j] = u32(t[j]);
        }
        if (i >= 4) {
#pragma unroll
            for (int j = 0; j < 3; ++j) sh[sl][x][7 + j] = u32(e2[j]);
        }
        __syncthreads();
        h2 aU0[4], aD0[4];
#pragma unroll
        for (int k = 0; k < 4; ++k) {
            aU0[k] = h2c(sh[sl][xu][k]);
            aD0[k] = h2c(sh[sl][xd][k]);
        }
        h2 tU[3] = {}, tD[3] = {}, m1_0[2] = {}, m2_0[2] = {};
        if (i >= 2) {
#pragma unroll
            for (int j = 0; j < 3; ++j) {
                tU[j] = h2c(sh[sl][xu][4 + j]);
                tD[j] = h2c(sh[sl][xd][4 + j]);
            }
            h2 vm0 = h2max3(t[0], tU[0], tD[0]);
            h2 vm1 = h2max3(t[1], tU[1], tD[1]);
            h2 vm2 = h2max3(t[2], tU[2], tD[2]);
            h2 mid01 = __builtin_shufflevector(vm0, vm1, 1, 2);
            h2 mid23 = __builtin_shufflevector(vm1, vm2, 1, 2);
            m1_0[0] = h2max3(vm0, mid01, vm1);   // m1(p-1) slots (0,1)
            m1_0[1] = h2max3(vm1, mid23, vm2);   // slots (2,3)
        }
        if (i >= 4) {
            h2 eU0 = h2c(sh[sl][xu][7]), eU1 = h2c(sh[sl][xu][8]), eU2 = h2c(sh[sl][xu][9]);
            h2 eD0 = h2c(sh[sl][xd][7]), eD1 = h2c(sh[sl][xd][8]), eD2 = h2c(sh[sl][xd][9]);
            h2 vm0 = h2max3(e2[0], eU0, eD0);
            h2 vm1 = h2max3(e2[1], eU1, eD1);
            h2 vm2 = h2max3(e2[2], eU2, eD2);
            h2 mid01 = __builtin_shufflevector(vm0, vm1, 1, 2);
            h2 mid23 = __builtin_shufflevector(vm1, vm2, 1, 2);
            m2_0[0] = h2max3(vm0, mid01, vm1);   // m2(p-2) slots (0,1)
            m2_0[1] = h2max3(vm1, mid23, vm2);
        }

        // ---- output z = p-3
        if (i >= 6) {
            const int offo = cbase + zo * PLANE;
            const bool zlo = (zo == 0);
            const bool zhi = (zo == Dn - 1);
            // D1(z) from m1(z-1)=m1M3, m1(z)=m1M2, m1(z+1)=m1M1
            h2 d1a0 = zlo ? m1M2[0] : m1M3[0];
            h2 d1a1 = zlo ? m1M2[1] : m1M3[1];
            h2 d1c0 = zhi ? m1M2[0] : m1M1[0];
            h2 d1c1 = zhi ? m1M2[1] : m1M1[1];
            h2 D1_0 = h2max3(d1a0, m1M2[0], d1c0);
            h2 D1_1 = h2max3(d1a1, m1M2[1], d1c1);
            // D2(z) from m2(z-1)=m2M2, m2(z)=m2M1, m2(z+1)=m2_0
            h2 d2a0 = zlo ? m2M1[0] : m2M2[0];
            h2 d2a1 = zlo ? m2M1[1] : m2M2[1];
            h2 d2c0 = zhi ? m2M1[0] : m2_0[0];
            h2 d2c1 = zhi ? m2M1[1] : m2_0[1];
            h2 D2_0 = h2max3(d2a0, m2M1[0], d2c0);
            h2 D2_1 = h2max3(d2a1, m2M1[1], d2c1);

            float ex[4] = {(float)xcM3[0].x, (float)xcM3[0].y,
                           (float)xcM3[1].x, (float)xcM3[1].y};
            float e1v[4] = {(float)e1cM2[0].x, (float)e1cM2[0].y,
                            (float)e1cM2[1].x, (float)e1cM2[1].y};
            float d1[4] = {(float)D1_0.x, (float)D1_0.y, (float)D1_1.x, (float)D1_1.y};
            float d2[4] = {(float)D2_0.x, (float)D2_0.y, (float)D2_1.x, (float)D2_1.y};
            float sv[4] = {(float)sP.x, (float)sP.y, (float)sP.z, (float)sP.w};
#pragma unroll
            for (int q = 0; q < 4; ++q) {
                float de1 = fmaxf(ex[q] - d1[q], 0.f);
                float s1 = FIRST ? de1 : (sv[q] + fmaxf(de1 - sv[q] * de1, 0.f));
                float de2 = fmaxf(e1v[q] - d2[q], 0.f);
                sv[q] = s1 + fmaxf(de2 - s1 * de2, 0.f);
            }
            Sout[offo] = (_Float16)sv[0];
            Sout[offo + Wn] = (_Float16)sv[1];
            Sout[offo + 2 * Wn] = (_Float16)sv[2];
            Sout[offo + 3 * Wn] = (_Float16)sv[3];
            Aout[offo] = e2cM1[0].x;               // A_{j+2}[z] = E2 center
            Aout[offo + Wn] = e2cM1[0].y;
            Aout[offo + 2 * Wn] = e2cM1[1].x;
            Aout[offo + 3 * Wn] = e2cM1[1].y;
        }

        // ---- rotate pipeline state
#pragma unroll
        for (int k = 0; k < 4; ++k) {
            aM2[k] = aM1[k]; aM1[k] = a0[k];
            hmM1[k] = hm0[k]; aUM1[k] = aU0[k]; aDM1[k] = aD0[k];
        }
#pragma unroll
        for (int j = 0; j < 3; ++j) {
            e1M2t[j] = e1M1t[j]; e1M1t[j] = t[j];
            hm1M1[j] = hm1_0[j]; e1UM1[j] = tU[j]; e1DM1[j] = tD[j];
        }
        m1M3[0] = m1M2[0]; m1M3[1] = m1M2[1];
        m1M2[0] = m1M1[0]; m1M2[1] = m1M1[1];
        m1M1[0] = m1_0[0]; m1M1[1] = m1_0[1];
        m2M2[0] = m2M1[0]; m2M2[1] = m2M1[1];
        m2M1[0] = m2_0[0]; m2M1[1] = m2_0[1];
        xcM3[0] = xcM2[0]; xcM3[1] = xcM2[1];
        xcM2[0] = xcM1[0]; xcM2[1] = xcM1[1];
        xcM1[0] = xc0[0];  xcM1[1] = xc0[1];
        e1cM2[0] = e1cM1[0]; e1cM2[1] = e1cM1[1];
        e1cM1[0] = e1c0[0]; e1cM1[1] = e1c0[1];
        e2cM1[0] = e2c0[0]; e2cM1[1] = e2c0[1];
        sP = sN;
    }
}

// ---------------- single-step kernel (R3-verified), used for final step ----
template <bool FIRST, bool LAST>
__global__ __launch_bounds__(192, 4) void step_k(const void* __restrict__ X_,
                                                 const _Float16* Sin,
                                                 void* Sout_,
                                                 _Float16* __restrict__ Aout) {
    const float* Xf = (const float*)X_;
    const _Float16* Xh = (const _Float16*)X_;
    _Float16* Sh = (_Float16*)Sout_;
    float* Sf = (float*)Sout_;

    const int bid = swizzle<NBLK / 8>((int)blockIdx.x);
    const int gy = bid % NYG;
    const int t2 = bid / NYG;
    const int zc = t2 % ZC;
    const int b = t2 / ZC;
    const int x = threadIdx.x;
    const int y0 = gy * 4;
    const int z0 = zc * ZPT;
    const int cbase = b * (Dn * PLANE) + y0 * Wn + x;

    int roff[8];
#pragma unroll
    for (int k = 0; k < 8; ++k) {
        int ry = y0 - 2 + k;
        ry = ry < 0 ? 0 : (ry > Hn - 1 ? Hn - 1 : ry);
        roff[k] = (ry - y0) * Wn;
    }

    __shared__ unsigned int sh[2][192][7];
    const int xu = (x < Wn - 1) ? x + 1 : x;
    const int xd = (x > 0) ? x - 1 : x;

    h2 aM2[3], aM1[3], hmM1[3], aUM1[3], aDM1[3];
    h2 xcM1[2], xcM2[2], e1cM1[2], mM1[2], mM2[2];

    _Float16 hP[8];
    float fP[8];
    h4 sP = {};

    auto issue = [&](int p) {
        int pz = p < 0 ? 0 : (p > Dn - 1 ? Dn - 1 : p);
        if (FIRST) {
            const float* pp = Xf + cbase + pz * PLANE;
#pragma unroll
            for (int k = 0; k < 8; ++k) fP[k] = pp[roff[k]];
        } else {
            const _Float16* pp = Xh + cbase + pz * PLANE;
#pragma unroll
            for (int k = 0; k < 8; ++k) hP[k] = pp[roff[k]];
        }
    };
    issue(z0 - 2);

#pragma unroll
    for (int i = 0; i < NITER1; ++i) {
        const int p = z0 - 2 + i;
        const int zo = p - 2;

        _Float16 s[8];
#pragma unroll
        for (int k = 0; k < 8; ++k) s[k] = FIRST ? (_Float16)fP[k] : hP[k];

        if (i + 1 < NITER1) issue(p + 1);

        h4 sN = {};
        if (!FIRST && i >= 3 && i + 1 < NITER1) {
            const _Float16* sp = Sin + cbase + (p - 1) * PLANE;
            sN.x = sp[0]; sN.y = sp[Wn]; sN.z = sp[2 * Wn]; sN.w = sp[3 * Wn];
        }

        h2 P[7];
#pragma unroll
        for (int k = 0; k < 7; ++k) { h2 t = {s[k], s[k + 1]}; P[k] = t; }
        h2 a0[3] = {P[1], P[3], P[5]};
        h2 hm0[3];
#pragma unroll
        for (int j = 0; j < 3; ++j)
            hm0[j] = h2min3(P[2 * j], P[2 * j + 1], P[2 * j + 2]);
        h2 xc0[2] = {P[2], P[4]};

        h2 e1[3];
        if (i >= 2) {
#pragma unroll
            for (int k = 0; k < 3; ++k)
                e1[k] = h2min3(h2min(hmM1[k], aM2[k]),
                               h2min(aUM1[k], aDM1[k]), a0[k]);
            if (gy == 0)       e1[0] = __builtin_shufflevector(e1[0], e1[0], 1, 1);
            if (gy == NYG - 1) e1[2] = __builtin_shufflevector(e1[2], e1[2], 0, 0);
        }

        const int sl = i & 1;
        sh[sl][x][0] = u32(a0[0]);
        sh[sl][x][1] = u32(a0[1]);
        sh[sl][x][2] = u32(a0[2]);
        if (i >= 2) {
            sh[sl][x][3] = u32(e1[0]);
            sh[sl][x][4] = u32(e1[1]);
            sh[sl][x][5] = u32(e1[2]);
        }
        __syncthreads();
        h2 aU0[3] = {h2c(sh[sl][xu][0]), h2c(sh[sl][xu][1]), h2c(sh[sl][xu][2])};
        h2 aD0[3] = {h2c(sh[sl][xd][0]), h2c(sh[sl][xd][1]), h2c(sh[sl][xd][2])};

        h2 m0[2], e1c0[2];
        if (i >= 2) {
            h2 eU0 = h2c(sh[sl][xu][3]), eU1 = h2c(sh[sl][xu][4]), eU2 = h2c(sh[sl][xu][5]);
            h2 eD0 = h2c(sh[sl][xd][3]), eD1 = h2c(sh[sl][xd][4]), eD2 = h2c(sh[sl][xd][5]);
            h2 vm0 = h2max3(e1[0], eU0, eD0);
            h2 vm1 = h2max3(e1[1], eU1, eD1);
            h2 vm2 = h2max3(e1[2], eU2, eD2);
            h2 mid01 = __builtin_shufflevector(vm0, vm1, 1, 2);
            h2 mid23 = __builtin_shufflevector(vm1, vm2, 1, 2);
            m0[0] = h2max3(vm0, mid01, vm1);
            m0[1] = h2max3(vm1, mid23, vm2);
            e1c0[0] = __builtin_shufflevector(e1[0], e1[1], 1, 2);
            e1c0[1] = __builtin_shufflevector(e1[1], e1[2], 1, 2);
        }

        if (i >= 4) {
            const int offo = cbase + zo * PLANE;
            const bool zlo = (zo == 0);
            const bool zhi = (zo == Dn - 1);
            h2 mzA0 = zlo ? mM1[0] : mM2[0];
            h2 mzA1 = zlo ? mM1[1] : mM2[1];
            h2 mzC0 = zhi ? mM1[0] : m0[0];
            h2 mzC1 = zhi ? mM1[1] : m0[1];
            h2 d01 = h2max3(mzA0, mM1[0], mzC0);
            h2 d23 = h2max3(mzA1, mM1[1], mzC1);

            float ex0 = (float)xcM2[0].x, ex1 = (float)xcM2[0].y;
            float ex2 = (float)xcM2[1].x, ex3 = (float)xcM2[1].y;
            float de0 = fmaxf(ex0 - (float)d01.x, 0.f);
            float de1 = fmaxf(ex1 - (float)d01.y, 0.f);
            float de2 = fmaxf(ex2 - (float)d23.x, 0.f);
            float de3 = fmaxf(ex3 - (float)d23.y, 0.f);
            float s0, s1, s2, s3;
            if (FIRST) {
                s0 = de0; s1 = de1; s2 = de2; s3 = de3;
            } else {
                s0 = (float)sP.x; s1 = (float)sP.y;
                s2 = (float)sP.z; s3 = (float)sP.w;
                s0 += fmaxf(de0 - s0 * de0, 0.f);
                s1 += fmaxf(de1 - s1 * de1, 0.f);
                s2 += fmaxf(de2 - s2 * de2, 0.f);
                s3 += fmaxf(de3 - s3 * de3, 0.f);
            }
            if (LAST) {
                Sf[offo] = s0; Sf[offo + Wn] = s1;
                Sf[offo + 2 * Wn] = s2; Sf[offo + 3 * Wn] = s3;
            } else {
                Sh[offo] = (_Float16)s0;
                Sh[offo + Wn] = (_Float16)s1;
                Sh[offo + 2 * Wn] = (_Float16)s2;
                Sh[offo + 3 * Wn] = (_Float16)s3;
                Aout[offo] = e1cM1[0].x;
                Aout[offo + Wn] = e1cM1[0].y;
                Aout[offo + 2 * Wn] = e1cM1[1].x;
                Aout[offo + 3 * Wn] = e1cM1[1].y;
            }
        }

#pragma unroll
        for (int k = 0; k < 3; ++k) {
            aM2[k] = aM1[k]; aM1[k] = a0[k];
            hmM1[k] = hm0[k]; aUM1[k] = aU0[k]; aDM1[k] = aD0[k];
        }
        xcM2[0] = xcM1[0]; xcM2[1] = xcM1[1];
        xcM1[0] = xc0[0];  xcM1[1] = xc0[1];
        if (i >= 2) {
            mM2[0] = mM1[0]; mM2[1] = mM1[1];
            mM1[0] = m0[0];  mM1[1] = m0[1];
            e1cM1[0] = e1c0[0]; e1cM1[1] = e1c0[1];
        }
        sP = sN;
    }
}

extern "C" void kernel_launch(void* const* d_in, const int* in_sizes, int n_in,
                              void* d_out, int out_size, void* d_ws, size_t ws_size,
                              hipStream_t stream) {
    const float* img = (const float*)d_in[0];
    _Float16* B0 = (_Float16*)d_ws;
    _Float16* B1 = B0 + TOTAL_ELEMS;
    _Float16* S  = B1 + TOTAL_ELEMS;   // 3 x 28.3 MB workspace (fp16)

    // 41 opening steps: fused pair (0,1) from fp32 img, 19 fused pairs
    // (2,3)..(38,39), single final step 40 writing fp32 to d_out.
    fused2_k<true><<<NBLK, 192, 0, stream>>>(img, nullptr, S, B0);   // -> A_2
    _Float16* a = B0;
    _Float16* nb = B1;
    for (int j = 0; j < 19; ++j) {
        fused2_k<false><<<NBLK, 192, 0, stream>>>(a, S, S, nb);
        _Float16* t = a; a = nb; nb = t;                              // -> A_40
    }
    step_k<false, true><<<NBLK, 192, 0, stream>>>(a, S, d_out, nullptr);
}

// Round 6
// 930.064 us; speedup vs baseline: 4.0444x; 1.0365x over previous
//
#include <hip/hip_runtime.h>

// Volume (B=2, C=1, D=192, H=192, W=192) fp32 in/out.
// R6 = R5 resubmit (R5 died to an infra failure, not a kernel fault), with
// the LDS-only barrier expressed as the guide's verified pattern:
//   asm("s_waitcnt lgkmcnt(0)") + __builtin_amdgcn_s_barrier()
// HIP's __syncthreads() emits "s_waitcnt vmcnt(0) lgkmcnt(0); s_barrier",
// which drained the per-plane global prefetch queue every iteration
// (R4 measured VALUBusy 47% = ~400 exposed cycles/plane). The barrier only
// needs to order LDS traffic (global loads are self-consumed; global stores
// never cross threads inside a kernel), so we skip the vmcnt drain;
// prefetches stay in flight across the barrier and the compiler's counted
// vmcnt waits before first use (next iteration) give a full iteration of
// latency cover.
//
// Everything else identical to R4 (verified absmax 0.0039):
// fused two-step kernel: E1=erode(X), D1=dilate(E1), delta1=relu(X-D1),
// E2=erode(E1), D2=dilate(E2), delta2=relu(E1-D2), both skel updates;
// writes A_{j+2} and S only. Thread=x (coalesced), h2 pairs along y,
// LDS x-halo (1 barrier/plane), z register pipeline (output z=p-3).

#define Dn 192
#define Hn 192
#define Wn 192
#define PLANE (Hn * Wn)
#define TOTAL_ELEMS (2 * Dn * Hn * Wn)
#define NYG (Hn / 4)         // 48 y-groups of 4 rows
#define ZPT 8                // z planes per thread
#define ZC (Dn / ZPT)        // 24 z-chunks
#define NBLK (NYG * ZC * 2)  // 2304 blocks
#define NITER2 (ZPT + 6)     // fused-2 pipeline iterations
#define NITER1 (ZPT + 4)     // single-step pipeline iterations

// LDS-only barrier: orders ds_write -> ds_read across the workgroup without
// draining outstanding global (vmcnt) prefetches. Memory clobber keeps DS
// memory ops on their side; s_barrier goes through the builtin so the
// compiler's convergence handling stays intact.
static __device__ __forceinline__ void lds_barrier() {
    asm volatile("s_waitcnt lgkmcnt(0)" ::: "memory");
    __builtin_amdgcn_s_barrier();
}

typedef _Float16 h2 __attribute__((ext_vector_type(2)));
typedef _Float16 h4 __attribute__((ext_vector_type(4)));

static __device__ __forceinline__ h2 h2min(h2 a, h2 b) { return __builtin_elementwise_min(a, b); }
static __device__ __forceinline__ h2 h2max(h2 a, h2 b) { return __builtin_elementwise_max(a, b); }
static __device__ __forceinline__ h2 h2min3(h2 a, h2 b, h2 c) { return h2min(h2min(a, b), c); }
static __device__ __forceinline__ h2 h2max3(h2 a, h2 b, h2 c) { return h2max(h2max(a, b), c); }
static __device__ __forceinline__ unsigned int u32(h2 v) { return __builtin_bit_cast(unsigned int, v); }
static __device__ __forceinline__ h2 h2c(unsigned int v) { return __builtin_bit_cast(h2, v); }

template <int CHUNK>
__device__ __forceinline__ int swizzle(int bid) {
    return (bid & 7) * CHUNK + (bid >> 3);
}

// ---------------- fused two-step kernel ----------------
template <bool FIRST>
__global__ __launch_bounds__(192, 4) void fused2_k(const void* __restrict__ X_,
                                                   const _Float16* Sin,
                                                   _Float16* Sout,
                                                   _Float16* __restrict__ Aout) {
    const float* Xf = (const float*)X_;
    const _Float16* Xh = (const _Float16*)X_;

    const int bid = swizzle<NBLK / 8>((int)blockIdx.x);
    const int gy = bid % NYG;
    const int t2 = bid / NYG;
    const int zc = t2 % ZC;
    const int b = t2 / ZC;
    const int x = threadIdx.x;         // 0..191, contiguous across lanes
    const int y0 = gy * 4;
    const int z0 = zc * ZPT;
    const int cbase = b * (Dn * PLANE) + y0 * Wn + x;

    // Clamped row offsets, rows y0-3 .. y0+6 (clamp = y-replicate boundary).
    int roff[10];
#pragma unroll
    for (int k = 0; k < 10; ++k) {
        int ry = y0 - 3 + k;
        ry = ry < 0 ? 0 : (ry > Hn - 1 ? Hn - 1 : ry);
        roff[k] = (ry - y0) * Wn;
    }

    // LDS: [slot][x][0..3]=X slots -2..5, [4..6]=E1 trimmed slots -1..4,
    // [7..9]=E2 slots -1..4. Stride 11 (gcd(11,32)=1 -> 2 lanes/bank, free).
    __shared__ unsigned int sh[2][192][11];
    const int xu = (x < Wn - 1) ? x + 1 : x;
    const int xd = (x > 0) ? x - 1 : x;

    // pipeline state (all zero-init; early-iteration consumers are gated)
    h2 aM1[4] = {}, aM2[4] = {}, hmM1[4] = {}, aUM1[4] = {}, aDM1[4] = {};
    h2 e1M1t[3] = {}, e1M2t[3] = {}, hm1M1[3] = {}, e1UM1[3] = {}, e1DM1[3] = {};
    h2 m1M1[2] = {}, m1M2[2] = {}, m1M3[2] = {};
    h2 m2M1[2] = {}, m2M2[2] = {};
    h2 xcM1[2] = {}, xcM2[2] = {}, xcM3[2] = {};
    h2 e1cM1[2] = {}, e1cM2[2] = {}, e2cM1[2] = {};
    h4 sP = {};

    _Float16 hP[10];
    float fP[10];
    auto issue = [&](int p) {
        int pz = p < 0 ? 0 : (p > Dn - 1 ? Dn - 1 : p);  // z-clamp (neutral)
        if (FIRST) {
            const float* pp = Xf + cbase + pz * PLANE;
#pragma unroll
            for (int k = 0; k < 10; ++k) fP[k] = pp[roff[k]];
        } else {
            const _Float16* pp = Xh + cbase + pz * PLANE;
#pragma unroll
            for (int k = 0; k < 10; ++k) hP[k] = pp[roff[k]];
        }
    };
    issue(z0 - 3);

#pragma unroll
    for (int i = 0; i < NITER2; ++i) {
        const int p = z0 - 3 + i;
        const int zo = p - 3;

        // ---- strip: 10 y-values [y0-3..y0+6] at (x, plane p)
        _Float16 s[10];
#pragma unroll
        for (int k = 0; k < 10; ++k) s[k] = FIRST ? (_Float16)fP[k] : hP[k];

        if (i + 1 < NITER2) issue(p + 1);

        // skel prefetch for NEXT iteration's output (plane p-2)
        h4 sN = {};
        if (!FIRST && i >= 5 && i + 1 < NITER2) {
            const _Float16* sp = Sin + cbase + (p - 2) * PLANE;
            sN.x = sp[0]; sN.y = sp[Wn]; sN.z = sp[2 * Wn]; sN.w = sp[3 * Wn];
        }

        // ---- per-plane X summaries
        h2 P[9];
#pragma unroll
        for (int k = 0; k < 9; ++k) { h2 t = {s[k], s[k + 1]}; P[k] = t; }
        h2 a0[4] = {P[1], P[3], P[5], P[7]};           // X slots -2..5
        h2 hm0[4];
#pragma unroll
        for (int j = 0; j < 4; ++j)
            hm0[j] = h2min3(P[2 * j], P[2 * j + 1], P[2 * j + 2]);  // y-min3, slots -2..5
        h2 xc0[2] = {P[3], P[5]};                      // X center slots 0..3

        // ---- E1(p-1) slots -2..5 ; trim t slots -1..4 ; hm1(p-1) ; e1c(p-1)
        h2 e1[4] = {}, t[3] = {}, hm1_0[3] = {}, e1c0[2] = {};
        if (i >= 2) {
#pragma unroll
            for (int k = 0; k < 4; ++k)
                e1[k] = h2min3(h2min(hmM1[k], aM2[k]),
                               h2min(aUM1[k], aDM1[k]), a0[k]);
            if (gy == 0) { h2 v = {e1[1].x, e1[1].x}; e1[0] = v; }
            if (gy == NYG - 1) { h2 v = {e1[2].y, e1[2].y}; e1[3] = v; }
            t[0] = __builtin_shufflevector(e1[0], e1[1], 1, 2);
            t[1] = __builtin_shufflevector(e1[1], e1[2], 1, 2);
            t[2] = __builtin_shufflevector(e1[2], e1[3], 1, 2);
            hm1_0[0] = h2min3(e1[0], t[0], e1[1]);
            hm1_0[1] = h2min3(e1[1], t[1], e1[2]);
            hm1_0[2] = h2min3(e1[2], t[2], e1[3]);
            e1c0[0] = e1[1]; e1c0[1] = e1[2];
        }

        // ---- E2(p-2) slots -1..4 ; e2c(p-2)
        h2 e2[3] = {}, e2c0[2] = {};
        if (i >= 4) {
#pragma unroll
            for (int j = 0; j < 3; ++j)
                e2[j] = h2min3(h2min(hm1M1[j], e1M2t[j]),
                               h2min(e1UM1[j], e1DM1[j]), t[j]);
            if (gy == 0) { h2 v = {e2[0].y, e2[0].y}; e2[0] = v; }
            if (gy == NYG - 1) { h2 v = {e2[2].x, e2[2].x}; e2[2] = v; }
            e2c0[0] = __builtin_shufflevector(e2[0], e2[1], 1, 2);
            e2c0[1] = __builtin_shufflevector(e2[1], e2[2], 1, 2);
        }

        // ---- LDS exchange (double-buffered, ONE LDS-only barrier per plane)
        const int sl = i & 1;
#pragma unroll
        for (int k = 0; k < 4; ++k) sh[sl][x][k] = u32(a0[k]);
        if (i >= 2) {
#pragma unroll
            for (int j = 0; j < 3; ++j) sh[sl][x][4 + j] = u32(t[j]);
        }
        if (i >= 4) {
#pragma unroll
            for (int j = 0; j < 3; ++j) sh[sl][x][7 + j] = u32(e2[j]);
        }
        lds_barrier();
        h2 aU0[4], aD0[4];
#pragma unroll
        for (int k = 0; k < 4; ++k) {
            aU0[k] = h2c(sh[sl][xu][k]);
            aD0[k] = h2c(sh[sl][xd][k]);
        }
        h2 tU[3] = {}, tD[3] = {}, m1_0[2] = {}, m2_0[2] = {};
        if (i >= 2) {
#pragma unroll
            for (int j = 0; j < 3; ++j) {
                tU[j] = h2c(sh[sl][xu][4 + j]);
                tD[j] = h2c(sh[sl][xd][4 + j]);
            }
            h2 vm0 = h2max3(t[0], tU[0], tD[0]);
            h2 vm1 = h2max3(t[1], tU[1], tD[1]);
            h2 vm2 = h2max3(t[2], tU[2], tD[2]);
            h2 mid01 = __builtin_shufflevector(vm0, vm1, 1, 2);
            h2 mid23 = __builtin_shufflevector(vm1, vm2, 1, 2);
            m1_0[0] = h2max3(vm0, mid01, vm1);   // m1(p-1) slots (0,1)
            m1_0[1] = h2max3(vm1, mid23, vm2);   // slots (2,3)
        }
        if (i >= 4) {
            h2 eU0 = h2c(sh[sl][xu][7]), eU1 = h2c(sh[sl][xu][8]), eU2 = h2c(sh[sl][xu][9]);
            h2 eD0 = h2c(sh[sl][xd][7]), eD1 = h2c(sh[sl][xd][8]), eD2 = h2c(sh[sl][xd][9]);
            h2 vm0 = h2max3(e2[0], eU0, eD0);
            h2 vm1 = h2max3(e2[1], eU1, eD1);
            h2 vm2 = h2max3(e2[2], eU2, eD2);
            h2 mid01 = __builtin_shufflevector(vm0, vm1, 1, 2);
            h2 mid23 = __builtin_shufflevector(vm1, vm2, 1, 2);
            m2_0[0] = h2max3(vm0, mid01, vm1);   // m2(p-2) slots (0,1)
            m2_0[1] = h2max3(vm1, mid23, vm2);
        }

        // ---- output z = p-3
        if (i >= 6) {
            const int offo = cbase + zo * PLANE;
            const bool zlo = (zo == 0);
            const bool zhi = (zo == Dn - 1);
            // D1(z) from m1(z-1)=m1M3, m1(z)=m1M2, m1(z+1)=m1M1
            h2 d1a0 = zlo ? m1M2[0] : m1M3[0];
            h2 d1a1 = zlo ? m1M2[1] : m1M3[1];
            h2 d1c0 = zhi ? m1M2[0] : m1M1[0];
            h2 d1c1 = zhi ? m1M2[1] : m1M1[1];
            h2 D1_0 = h2max3(d1a0, m1M2[0], d1c0);
            h2 D1_1 = h2max3(d1a1, m1M2[1], d1c1);
            // D2(z) from m2(z-1)=m2M2, m2(z)=m2M1, m2(z+1)=m2_0
            h2 d2a0 = zlo ? m2M1[0] : m2M2[0];
            h2 d2a1 = zlo ? m2M1[1] : m2M2[1];
            h2 d2c0 = zhi ? m2M1[0] : m2_0[0];
            h2 d2c1 = zhi ? m2M1[1] : m2_0[1];
            h2 D2_0 = h2max3(d2a0, m2M1[0], d2c0);
            h2 D2_1 = h2max3(d2a1, m2M1[1], d2c1);

            float ex[4] = {(float)xcM3[0].x, (float)xcM3[0].y,
                           (float)xcM3[1].x, (float)xcM3[1].y};
            float e1v[4] = {(float)e1cM2[0].x, (float)e1cM2[0].y,
                            (float)e1cM2[1].x, (float)e1cM2[1].y};
            float d1[4] = {(float)D1_0.x, (float)D1_0.y, (float)D1_1.x, (float)D1_1.y};
            float d2[4] = {(float)D2_0.x, (float)D2_0.y, (float)D2_1.x, (float)D2_1.y};
            float sv[4] = {(float)sP.x, (float)sP.y, (float)sP.z, (float)sP.w};
#pragma unroll
            for (int q = 0; q < 4; ++q) {
                float de1 = fmaxf(ex[q] - d1[q], 0.f);
                float s1 = FIRST ? de1 : (sv[q] + fmaxf(de1 - sv[q] * de1, 0.f));
                float de2 = fmaxf(e1v[q] - d2[q], 0.f);
                sv[q] = s1 + fmaxf(de2 - s1 * de2, 0.f);
            }
            Sout[offo] = (_Float16)sv[0];
            Sout[offo + Wn] = (_Float16)sv[1];
            Sout[offo + 2 * Wn] = (_Float16)sv[2];
            Sout[offo + 3 * Wn] = (_Float16)sv[3];
            Aout[offo] = e2cM1[0].x;               // A_{j+2}[z] = E2 center
            Aout[offo + Wn] = e2cM1[0].y;
            Aout[offo + 2 * Wn] = e2cM1[1].x;
            Aout[offo + 3 * Wn] = e2cM1[1].y;
        }

        // ---- rotate pipeline state
#pragma unroll
        for (int k = 0; k < 4; ++k) {
            aM2[k] = aM1[k]; aM1[k] = a0[k];
            hmM1[k] = hm0[k]; aUM1[k] = aU0[k]; aDM1[k] = aD0[k];
        }
#pragma unroll
        for (int j = 0; j < 3; ++j) {
            e1M2t[j] = e1M1t[j]; e1M1t[j] = t[j];
            hm1M1[j] = hm1_0[j]; e1UM1[j] = tU[j]; e1DM1[j] = tD[j];
        }
        m1M3[0] = m1M2[0]; m1M3[1] = m1M2[1];
        m1M2[0] = m1M1[0]; m1M2[1] = m1M1[1];
        m1M1[0] = m1_0[0]; m1M1[1] = m1_0[1];
        m2M2[0] = m2M1[0]; m2M2[1] = m2M1[1];
        m2M1[0] = m2_0[0]; m2M1[1] = m2_0[1];
        xcM3[0] = xcM2[0]; xcM3[1] = xcM2[1];
        xcM2[0] = xcM1[0]; xcM2[1] = xcM1[1];
        xcM1[0] = xc0[0];  xcM1[1] = xc0[1];
        e1cM2[0] = e1cM1[0]; e1cM2[1] = e1cM1[1];
        e1cM1[0] = e1c0[0]; e1cM1[1] = e1c0[1];
        e2cM1[0] = e2c0[0]; e2cM1[1] = e2c0[1];
        sP = sN;
    }
}

// ---------------- single-step kernel (R3-verified), used for final step ----
template <bool FIRST, bool LAST>
__global__ __launch_bounds__(192, 4) void step_k(const void* __restrict__ X_,
                                                 const _Float16* Sin,
                                                 void* Sout_,
                                                 _Float16* __restrict__ Aout) {
    const float* Xf = (const float*)X_;
    const _Float16* Xh = (const _Float16*)X_;
    _Float16* Sh = (_Float16*)Sout_;
    float* Sf = (float*)Sout_;

    const int bid = swizzle<NBLK / 8>((int)blockIdx.x);
    const int gy = bid % NYG;
    const int t2 = bid / NYG;
    const int zc = t2 % ZC;
    const int b = t2 / ZC;
    const int x = threadIdx.x;
    const int y0 = gy * 4;
    const int z0 = zc * ZPT;
    const int cbase = b * (Dn * PLANE) + y0 * Wn + x;

    int roff[8];
#pragma unroll
    for (int k = 0; k < 8; ++k) {
        int ry = y0 - 2 + k;
        ry = ry < 0 ? 0 : (ry > Hn - 1 ? Hn - 1 : ry);
        roff[k] = (ry - y0) * Wn;
    }

    __shared__ unsigned int sh[2][192][7];
    const int xu = (x < Wn - 1) ? x + 1 : x;
    const int xd = (x > 0) ? x - 1 : x;

    h2 aM2[3], aM1[3], hmM1[3], aUM1[3], aDM1[3];
    h2 xcM1[2], xcM2[2], e1cM1[2], mM1[2], mM2[2];

    _Float16 hP[8];
    float fP[8];
    h4 sP = {};

    auto issue = [&](int p) {
        int pz = p < 0 ? 0 : (p > Dn - 1 ? Dn - 1 : p);
        if (FIRST) {
            const float* pp = Xf + cbase + pz * PLANE;
#pragma unroll
            for (int k = 0; k < 8; ++k) fP[k] = pp[roff[k]];
        } else {
            const _Float16* pp = Xh + cbase + pz * PLANE;
#pragma unroll
            for (int k = 0; k < 8; ++k) hP[k] = pp[roff[k]];
        }
    };
    issue(z0 - 2);

#pragma unroll
    for (int i = 0; i < NITER1; ++i) {
        const int p = z0 - 2 + i;
        const int zo = p - 2;

        _Float16 s[8];
#pragma unroll
        for (int k = 0; k < 8; ++k) s[k] = FIRST ? (_Float16)fP[k] : hP[k];

        if (i + 1 < NITER1) issue(p + 1);

        h4 sN = {};
        if (!FIRST && i >= 3 && i + 1 < NITER1) {
            const _Float16* sp = Sin + cbase + (p - 1) * PLANE;
            sN.x = sp[0]; sN.y = sp[Wn]; sN.z = sp[2 * Wn]; sN.w = sp[3 * Wn];
        }

        h2 P[7];
#pragma unroll
        for (int k = 0; k < 7; ++k) { h2 t = {s[k], s[k + 1]}; P[k] = t; }
        h2 a0[3] = {P[1], P[3], P[5]};
        h2 hm0[3];
#pragma unroll
        for (int j = 0; j < 3; ++j)
            hm0[j] = h2min3(P[2 * j], P[2 * j + 1], P[2 * j + 2]);
        h2 xc0[2] = {P[2], P[4]};

        h2 e1[3];
        if (i >= 2) {
#pragma unroll
            for (int k = 0; k < 3; ++k)
                e1[k] = h2min3(h2min(hmM1[k], aM2[k]),
                               h2min(aUM1[k], aDM1[k]), a0[k]);
            if (gy == 0)       e1[0] = __builtin_shufflevector(e1[0], e1[0], 1, 1);
            if (gy == NYG - 1) e1[2] = __builtin_shufflevector(e1[2], e1[2], 0, 0);
        }

        const int sl = i & 1;
        sh[sl][x][0] = u32(a0[0]);
        sh[sl][x][1] = u32(a0[1]);
        sh[sl][x][2] = u32(a0[2]);
        if (i >= 2) {
            sh[sl][x][3] = u32(e1[0]);
            sh[sl][x][4] = u32(e1[1]);
            sh[sl][x][5] = u32(e1[2]);
        }
        lds_barrier();
        h2 aU0[3] = {h2c(sh[sl][xu][0]), h2c(sh[sl][xu][1]), h2c(sh[sl][xu][2])};
        h2 aD0[3] = {h2c(sh[sl][xd][0]), h2c(sh[sl][xd][1]), h2c(sh[sl][xd][2])};

        h2 m0[2], e1c0[2];
        if (i >= 2) {
            h2 eU0 = h2c(sh[sl][xu][3]), eU1 = h2c(sh[sl][xu][4]), eU2 = h2c(sh[sl][xu][5]);
            h2 eD0 = h2c(sh[sl][xd][3]), eD1 = h2c(sh[sl][xd][4]), eD2 = h2c(sh[sl][xd][5]);
            h2 vm0 = h2max3(e1[0], eU0, eD0);
            h2 vm1 = h2max3(e1[1], eU1, eD1);
            h2 vm2 = h2max3(e1[2], eU2, eD2);
            h2 mid01 = __builtin_shufflevector(vm0, vm1, 1, 2);
            h2 mid23 = __builtin_shufflevector(vm1, vm2, 1, 2);
            m0[0] = h2max3(vm0, mid01, vm1);
            m0[1] = h2max3(vm1, mid23, vm2);
            e1c0[0] = __builtin_shufflevector(e1[0], e1[1], 1, 2);
            e1c0[1] = __builtin_shufflevector(e1[1], e1[2], 1, 2);
        }

        if (i >= 4) {
            const int offo = cbase + zo * PLANE;
            const bool zlo = (zo == 0);
            const bool zhi = (zo == Dn - 1);
            h2 mzA0 = zlo ? mM1[0] : mM2[0];
            h2 mzA1 = zlo ? mM1[1] : mM2[1];
            h2 mzC0 = zhi ? mM1[0] : m0[0];
            h2 mzC1 = zhi ? mM1[1] : m0[1];
            h2 d01 = h2max3(mzA0, mM1[0], mzC0);
            h2 d23 = h2max3(mzA1, mM1[1], mzC1);

            float ex0 = (float)xcM2[0].x, ex1 = (float)xcM2[0].y;
            float ex2 = (float)xcM2[1].x, ex3 = (float)xcM2[1].y;
            float de0 = fmaxf(ex0 - (float)d01.x, 0.f);
            float de1 = fmaxf(ex1 - (float)d01.y, 0.f);
            float de2 = fmaxf(ex2 - (float)d23.x, 0.f);
            float de3 = fmaxf(ex3 - (float)d23.y, 0.f);
            float s0, s1, s2, s3;
            if (FIRST) {
                s0 = de0; s1 = de1; s2 = de2; s3 = de3;
            } else {
                s0 = (float)sP.x; s1 = (float)sP.y;
                s2 = (float)sP.z; s3 = (float)sP.w;
                s0 += fmaxf(de0 - s0 * de0, 0.f);
                s1 += fmaxf(de1 - s1 * de1, 0.f);
                s2 += fmaxf(de2 - s2 * de2, 0.f);
                s3 += fmaxf(de3 - s3 * de3, 0.f);
            }
            if (LAST) {
                Sf[offo] = s0; Sf[offo + Wn] = s1;
                Sf[offo + 2 * Wn] = s2; Sf[offo + 3 * Wn] = s3;
            } else {
                Sh[offo] = (_Float16)s0;
                Sh[offo + Wn] = (_Float16)s1;
                Sh[offo + 2 * Wn] = (_Float16)s2;
                Sh[offo + 3 * Wn] = (_Float16)s3;
                Aout[offo] = e1cM1[0].x;
                Aout[offo + Wn] = e1cM1[0].y;
                Aout[offo + 2 * Wn] = e1cM1[1].x;
                Aout[offo + 3 * Wn] = e1cM1[1].y;
            }
        }

#pragma unroll
        for (int k = 0; k < 3; ++k) {
            aM2[k] = aM1[k]; aM1[k] = a0[k];
            hmM1[k] = hm0[k]; aUM1[k] = aU0[k]; aDM1[k] = aD0[k];
        }
        xcM2[0] = xcM1[0]; xcM2[1] = xcM1[1];
        xcM1[0] = xc0[0];  xcM1[1] = xc0[1];
        if (i >= 2) {
            mM2[0] = mM1[0]; mM2[1] = mM1[1];
            mM1[0] = m0[0];  mM1[1] = m0[1];
            e1cM1[0] = e1c0[0]; e1cM1[1] = e1c0[1];
        }
        sP = sN;
    }
}

extern "C" void kernel_launch(void* const* d_in, const int* in_sizes, int n_in,
                              void* d_out, int out_size, void* d_ws, size_t ws_size,
                              hipStream_t stream) {
    const float* img = (const float*)d_in[0];
    _Float16* B0 = (_Float16*)d_ws;
    _Float16* B1 = B0 + TOTAL_ELEMS;
    _Float16* S  = B1 + TOTAL_ELEMS;   // 3 x 28.3 MB workspace (fp16)

    // 41 opening steps: fused pair (0,1) from fp32 img, 19 fused pairs
    // (2,3)..(38,39), single final step 40 writing fp32 to d_out.
    fused2_k<true><<<NBLK, 192, 0, stream>>>(img, nullptr, S, B0);   // -> A_2
    _Float16* a = B0;
    _Float16* nb = B1;
    for (int j = 0; j < 19; ++j) {
        fused2_k<false><<<NBLK, 192, 0, stream>>>(a, S, S, nb);
        _Float16* t = a; a = nb; nb = t;                              // -> A_40
    }
    step_k<false, true><<<NBLK, 192, 0, stream>>>(a, S, d_out, nullptr);
}